// Round 7
// baseline (55.896 us; speedup 1.0000x reference)
//
#include <hip/hip_runtime.h>
#include <hip/hip_bf16.h>

typedef __attribute__((ext_vector_type(8))) short short8;
typedef __attribute__((ext_vector_type(4))) float f32x4;

// fp32 -> bf16 round-to-nearest-even (finite inputs)
__device__ __forceinline__ unsigned short f2bf(float f) {
    union { float f; unsigned int u; } v; v.f = f;
    unsigned int u = v.u;
    u = (u + 0x7FFFu + ((u >> 16) & 1u)) >> 16;
    return (unsigned short)u;
}

// 8x f32 -> short8 bf16 via packed RNE converts (v_cvt_pk_bf16_f32)
__device__ __forceinline__ short8 cvt8(const f32x4 a, const f32x4 b) {
    union { __hip_bfloat162 h[4]; short8 s; } r;
    r.h[0] = __float22bfloat162_rn(make_float2(a[0], a[1]));
    r.h[1] = __float22bfloat162_rn(make_float2(a[2], a[3]));
    r.h[2] = __float22bfloat162_rn(make_float2(b[0], b[1]));
    r.h[3] = __float22bfloat162_rn(make_float2(b[2], b[3]));
    return r.s;
}

// ---------------------------------------------------------------------------
// Kernel 1: x[b][c][h][w] f32 -> xt[h][w][c][b] bf16.
// 1024 blocks (h x cgroup x b-quarter) = 4 blocks/CU for streaming TLP.
// ---------------------------------------------------------------------------
__global__ __launch_bounds__(256) void k_xt(const float* __restrict__ x,
                                            unsigned short* __restrict__ xt) {
    const int h  = blockIdx.x;   // 0..31
    const int cg = blockIdx.y;   // 0..7
    const int bq = blockIdx.z;   // 0..3
    const int t  = threadIdx.x;
    __shared__ unsigned short L[32 * 136];  // [w][c*16+b], padded stride

    #pragma unroll
    for (int i = 0; i < 4; ++i) {
        int s   = t + i * 256;        // 0..1023
        int row = s >> 3;             // 0..127 -> (b,c)
        int wq  = s & 7;
        int b = row >> 3, c = row & 7;
        const f32x4 v = *(const f32x4*)(x + (((size_t)((bq * 16 + b) * 64 + cg * 8 + c) * 32 + h) * 32 + wq * 4));
        int base = c * 16 + b;
        L[(wq * 4 + 0) * 136 + base] = f2bf(v[0]);
        L[(wq * 4 + 1) * 136 + base] = f2bf(v[1]);
        L[(wq * 4 + 2) * 136 + base] = f2bf(v[2]);
        L[(wq * 4 + 3) * 136 + base] = f2bf(v[3]);
    }
    __syncthreads();
    #pragma unroll
    for (int i = 0; i < 2; ++i) {
        int s  = t + i * 256;   // 0..511
        int w  = s >> 4;        // 0..31
        int c  = (s >> 1) & 7;  // 0..7
        int b8 = s & 1;         // 0..1
        short8 v = *(const short8*)&L[w * 136 + c * 16 + b8 * 8];
        *(short8*)(xt + (((size_t)(h * 32 + w) * 64 + cg * 8 + c) * 64 + bq * 16 + b8 * 8)) = v;
    }
}

// ---------------------------------------------------------------------------
// Kernel 2: per-location GEMM + DIRECT output store. 1024 blocks (one per l),
// 256 threads, 4 blocks/CU. Double-buffered LDS; 2-round-deep prefetch; raw
// barrier, loads stay in flight. Epilogue writes out[m][l] directly as 4-B
// stores — XCD swizzle keeps all 16 writers of each 64-B line concurrently
// resident on one XCD, so lines merge in that XCD's write-back L2.
// ---------------------------------------------------------------------------
__global__ __launch_bounds__(256, 4) void k_main(const float* __restrict__ wgt,
                                                 const unsigned short* __restrict__ xt,
                                                 const float* __restrict__ bias,
                                                 float* __restrict__ out) {
    const int bid = blockIdx.x;
    const int l   = (bid & 7) * 128 + (bid >> 3);   // bijective XCD swizzle
    const int oh = l >> 5, ow = l & 31;
    const int t  = threadIdx.x;
    const int wave = t >> 6, lane = t & 63;
    const int wm = wave >> 1, wn = wave & 1;

    __shared__ unsigned short Ash[2][64 * 72];  // [b][k], +8 pad
    __shared__ unsigned short Bsh[2][64 * 72];  // [o][k], +8 pad

    f32x4 acc[2][2];
    #pragma unroll
    for (int i = 0; i < 2; ++i)
        #pragma unroll
        for (int j = 0; j < 2; ++j)
            acc[i][j] = (f32x4){0.f, 0.f, 0.f, 0.f};

    const int b0 = wave * 16;
    const int o  = t >> 2, kp = t & 3;
    const float* bbase = wgt + (size_t)l * 36864 + o * 576 + kp * 16;

    auto loadA = [&](int kt, short8& va, short8& vb) {
        int kk = kt * 64 + lane;      // 0..575
        int c  = kk / 9;
        int r  = kk - c * 9;
        int kh = r / 3;
        int kw = r - kh * 3;
        int hh = oh + kh - 1;
        int ww = ow + kw - 1;
        va = (short8){0,0,0,0,0,0,0,0};
        vb = (short8){0,0,0,0,0,0,0,0};
        if ((unsigned)hh < 32u && (unsigned)ww < 32u) {
            const unsigned short* src = xt + (((size_t)(hh * 32 + ww) * 64 + c) * 64 + b0);
            va = *(const short8*)src;
            vb = *(const short8*)(src + 8);
        }
    };
    auto loadB = [&](int kt, f32x4 (&bf)[4]) {
        const f32x4* bp = (const f32x4*)(bbase + kt * 64);
        bf[0] = bp[0]; bf[1] = bp[1]; bf[2] = bp[2]; bf[3] = bp[3];
    };

    // 2-deep prefetch slots (all indices static after full unroll)
    short8 pA0[2], pA1[2];
    f32x4 bf[2][4];
    short8 bq0, bq1;

    loadA(0, pA0[0], pA1[0]);
    loadB(0, bf[0]);
    loadA(1, pA0[1], pA1[1]);
    loadB(1, bf[1]);
    bq0 = cvt8(bf[0][0], bf[0][1]);
    bq1 = cvt8(bf[0][2], bf[0][3]);

    #pragma unroll
    for (int kt = 0; kt < 9; ++kt) {
        const int p = kt & 1;
        // B slot p was consumed by cvt at end of round kt-1 -> refill with kt+2
        if (kt + 2 < 9) loadB(kt + 2, bf[p]);
        // stage A ([b][k] b16 scatter) — vmcnt wait for round-kt A lands here
        #pragma unroll
        for (int j = 0; j < 8; ++j) Ash[p][(b0 + j) * 72 + lane] = (unsigned short)pA0[p][j];
        #pragma unroll
        for (int j = 0; j < 8; ++j) Ash[p][(b0 + 8 + j) * 72 + lane] = (unsigned short)pA1[p][j];
        // A slot p consumed -> refill with kt+2
        if (kt + 2 < 9) loadA(kt + 2, pA0[p], pA1[p]);
        // stage B (pre-converted registers)
        {
            unsigned short* bdst = &Bsh[p][o * 72 + kp * 16];
            *(short8*)bdst       = bq0;
            *(short8*)(bdst + 8) = bq1;
        }
        // own LDS writes visible, then barrier; do NOT drain vmcnt
        asm volatile("s_waitcnt lgkmcnt(0)" ::: "memory");
        __builtin_amdgcn_s_barrier();
        __builtin_amdgcn_sched_barrier(0);
        // MFMA phase
        #pragma unroll
        for (int ks = 0; ks < 2; ++ks) {
            int kof = ks * 32 + (lane >> 4) * 8;
            short8 a0 = *(const short8*)&Ash[p][(wm * 32 + (lane & 15)) * 72 + kof];
            short8 a1 = *(const short8*)&Ash[p][(wm * 32 + 16 + (lane & 15)) * 72 + kof];
            short8 q0 = *(const short8*)&Bsh[p][(wn * 32 + (lane & 15)) * 72 + kof];
            short8 q1 = *(const short8*)&Bsh[p][(wn * 32 + 16 + (lane & 15)) * 72 + kof];
            acc[0][0] = __builtin_amdgcn_mfma_f32_16x16x32_bf16(a0, q0, acc[0][0], 0, 0, 0);
            acc[0][1] = __builtin_amdgcn_mfma_f32_16x16x32_bf16(a0, q1, acc[0][1], 0, 0, 0);
            acc[1][0] = __builtin_amdgcn_mfma_f32_16x16x32_bf16(a1, q0, acc[1][0], 0, 0, 0);
            acc[1][1] = __builtin_amdgcn_mfma_f32_16x16x32_bf16(a1, q1, acc[1][1], 0, 0, 0);
        }
        // convert next round's B (its loads are ~2 rounds old -> no stall)
        if (kt + 1 < 9) {
            bq0 = cvt8(bf[(kt + 1) & 1][0], bf[(kt + 1) & 1][1]);
            bq1 = cvt8(bf[(kt + 1) & 1][2], bf[(kt + 1) & 1][3]);
        }
    }

    // epilogue: +bias, DIRECT f32 store out[m][l] (L2 merges the 64-B lines
    // across the 16 co-resident same-XCD blocks covering l..l+15)
    const int col = lane & 15;
    const int rq  = (lane >> 4) * 4;
    #pragma unroll
    for (int j = 0; j < 2; ++j) {
        int n = wn * 32 + j * 16 + col;
        float bv = bias[n * 1024 + l];
        #pragma unroll
        for (int i = 0; i < 2; ++i) {
            int mbase = wm * 32 + i * 16 + rq;
            #pragma unroll
            for (int q = 0; q < 4; ++q) {
                out[(size_t)((mbase + q) * 64 + n) * 1024 + l] = acc[i][j][q] + bv;
            }
        }
    }
}

// ---------------------------------------------------------------------------
// Fallback: naive direct conv (used only if ws_size too small)
// ---------------------------------------------------------------------------
__global__ __launch_bounds__(256) void k_naive(const float* __restrict__ x,
                                               const float* __restrict__ wgt,
                                               const float* __restrict__ bias,
                                               float* __restrict__ out) {
    int idx = blockIdx.x * 256 + threadIdx.x;
    int ow = idx & 31, oh = (idx >> 5) & 31, o = (idx >> 10) & 63, b = idx >> 16;
    float acc = bias[(o * 32 + oh) * 32 + ow];
    const float* wp = wgt + ((size_t)(oh * 32 + ow) * 64 + o) * 576;
    for (int c = 0; c < 64; ++c) {
        for (int kh = 0; kh < 3; ++kh) {
            int hh = oh + kh - 1;
            if ((unsigned)hh >= 32u) continue;
            for (int kw = 0; kw < 3; ++kw) {
                int ww = ow + kw - 1;
                if ((unsigned)ww >= 32u) continue;
                acc += x[((size_t)(b * 64 + c) * 32 + hh) * 32 + ww] * wp[c * 9 + kh * 3 + kw];
            }
        }
    }
    out[idx] = acc;
}

extern "C" void kernel_launch(void* const* d_in, const int* in_sizes, int n_in,
                              void* d_out, int out_size, void* d_ws, size_t ws_size,
                              hipStream_t stream) {
    const float* x    = (const float*)d_in[0];
    const float* wgt  = (const float*)d_in[1];
    const float* bias = (const float*)d_in[2];
    float* out = (float*)d_out;

    const size_t xt_bytes = (size_t)32 * 32 * 64 * 64 * 2;   // 8.39 MB

    if (ws_size >= xt_bytes) {
        unsigned short* xt = (unsigned short*)d_ws;
        k_xt<<<dim3(32, 8, 4), 256, 0, stream>>>(x, xt);
        k_main<<<1024, 256, 0, stream>>>(wgt, xt, bias, out);
    } else {
        k_naive<<<(64 * 64 * 32 * 32) / 256, 256, 0, stream>>>(x, wgt, bias, out);
    }
}

// Round 10
// 46.211 us; speedup vs baseline: 1.2096x; 1.2096x over previous
//
#include <hip/hip_runtime.h>
#include <hip/hip_bf16.h>

typedef __attribute__((ext_vector_type(8))) short short8;
typedef __attribute__((ext_vector_type(4))) short short4_t;
typedef __attribute__((ext_vector_type(4))) float f32x4;

// fp32 -> bf16 round-to-nearest-even (finite inputs)
__device__ __forceinline__ unsigned short f2bf(float f) {
    union { float f; unsigned int u; } v; v.f = f;
    unsigned int u = v.u;
    u = (u + 0x7FFFu + ((u >> 16) & 1u)) >> 16;
    return (unsigned short)u;
}

// 4x f32 -> short4 bf16 via packed RNE converts (v_cvt_pk_bf16_f32)
__device__ __forceinline__ short4_t cvt4(const f32x4 a) {
    union { __hip_bfloat162 h[2]; short4_t s; } r;
    r.h[0] = __float22bfloat162_rn(make_float2(a[0], a[1]));
    r.h[1] = __float22bfloat162_rn(make_float2(a[2], a[3]));
    return r.s;
}

// ---------------------------------------------------------------------------
// Kernel 1: x[b][c][h][w] f32 -> xt[h][w][c][b] bf16.
// 1024 blocks (h x cgroup x b-quarter) = 4 blocks/CU for streaming TLP.
// ---------------------------------------------------------------------------
__global__ __launch_bounds__(256) void k_xt(const float* __restrict__ x,
                                            unsigned short* __restrict__ xt) {
    const int h  = blockIdx.x;   // 0..31
    const int cg = blockIdx.y;   // 0..7
    const int bq = blockIdx.z;   // 0..3
    const int t  = threadIdx.x;
    __shared__ unsigned short L[32 * 136];  // [w][c*16+b], padded stride

    #pragma unroll
    for (int i = 0; i < 4; ++i) {
        int s   = t + i * 256;        // 0..1023
        int row = s >> 3;             // 0..127 -> (b,c)
        int wq  = s & 7;
        int b = row >> 3, c = row & 7;
        const f32x4 v = *(const f32x4*)(x + (((size_t)((bq * 16 + b) * 64 + cg * 8 + c) * 32 + h) * 32 + wq * 4));
        int base = c * 16 + b;
        L[(wq * 4 + 0) * 136 + base] = f2bf(v[0]);
        L[(wq * 4 + 1) * 136 + base] = f2bf(v[1]);
        L[(wq * 4 + 2) * 136 + base] = f2bf(v[2]);
        L[(wq * 4 + 3) * 136 + base] = f2bf(v[3]);
    }
    __syncthreads();
    #pragma unroll
    for (int i = 0; i < 2; ++i) {
        int s  = t + i * 256;   // 0..511
        int w  = s >> 4;        // 0..31
        int c  = (s >> 1) & 7;  // 0..7
        int b8 = s & 1;         // 0..1
        short8 v = *(const short8*)&L[w * 136 + c * 16 + b8 * 8];
        *(short8*)(xt + (((size_t)(h * 32 + w) * 64 + cg * 8 + c) * 64 + bq * 16 + b8 * 8)) = v;
    }
}

// ---------------------------------------------------------------------------
// Kernel 2: per-location GEMM. 1024 blocks (one per l), 256 threads,
// 4 blocks/CU. Double-buffered LDS; 2-deep prefetch; raw barrier, loads stay
// in flight. loadB uses chunk-order mapping: each global_load_dwordx4 has
// lanes 0-15 covering one o-row's 256 B contiguously (16 B/lane packed
// sectors) — 4x fewer TA sector-requests than the o-major mapping.
// Writes ws2b[l][b][o] bf16 coalesced.
// ---------------------------------------------------------------------------
__global__ __launch_bounds__(256, 4) void k_main(const float* __restrict__ wgt,
                                                 const unsigned short* __restrict__ xt,
                                                 const float* __restrict__ bias,
                                                 unsigned short* __restrict__ ws2b) {
    const int bid = blockIdx.x;
    const int l   = (bid & 7) * 128 + (bid >> 3);   // bijective XCD swizzle
    const int oh = l >> 5, ow = l & 31;
    const int t  = threadIdx.x;
    const int wave = t >> 6, lane = t & 63;
    const int wm = wave >> 1, wn = wave & 1;

    __shared__ unsigned short Ash[2][64 * 72];  // [b][k], +8 pad
    __shared__ unsigned short Bsh[2][64 * 72];  // [o][k], +8 pad

    f32x4 acc[2][2];
    #pragma unroll
    for (int i = 0; i < 2; ++i)
        #pragma unroll
        for (int j = 0; j < 2; ++j)
            acc[i][j] = (f32x4){0.f, 0.f, 0.f, 0.f};

    const int b0 = wave * 16;
    // B chunk-order mapping: instruction i reads o_i = i*16 + (t>>4), 16 B at
    // k-chunk c16 = t&15 (floats c16*4..+3 of the round's 64-k slab).
    const int orow = t >> 4;        // 0..15
    const int c16  = t & 15;        // 0..15
    const float* wb = wgt + (size_t)l * 36864 + (size_t)orow * 576 + c16 * 4;

    auto loadA = [&](int kt, short8& va, short8& vb) {
        int kk = kt * 64 + lane;      // 0..575
        int c  = kk / 9;
        int r  = kk - c * 9;
        int kh = r / 3;
        int kw = r - kh * 3;
        int hh = oh + kh - 1;
        int ww = ow + kw - 1;
        va = (short8){0,0,0,0,0,0,0,0};
        vb = (short8){0,0,0,0,0,0,0,0};
        if ((unsigned)hh < 32u && (unsigned)ww < 32u) {
            const unsigned short* src = xt + (((size_t)(hh * 32 + ww) * 64 + c) * 64 + b0);
            va = *(const short8*)src;
            vb = *(const short8*)(src + 8);
        }
    };
    auto loadB = [&](int kt, f32x4 (&bf)[4]) {
        #pragma unroll
        for (int i = 0; i < 4; ++i)
            bf[i] = *(const f32x4*)(wb + (size_t)i * (16 * 576) + kt * 64);
    };

    // 2-deep prefetch slots (all indices static after full unroll)
    short8 pA0[2], pA1[2];
    f32x4 bf[2][4];
    short4_t bq[4];

    loadA(0, pA0[0], pA1[0]);
    loadB(0, bf[0]);
    loadA(1, pA0[1], pA1[1]);
    loadB(1, bf[1]);
    #pragma unroll
    for (int i = 0; i < 4; ++i) bq[i] = cvt4(bf[0][i]);

    #pragma unroll
    for (int kt = 0; kt < 9; ++kt) {
        const int p = kt & 1;
        // B slot p consumed by cvt at end of round kt-1 -> refill with kt+2
        if (kt + 2 < 9) loadB(kt + 2, bf[p]);
        // stage A ([b][k] b16 scatter) — vmcnt wait for round-kt A lands here
        #pragma unroll
        for (int j = 0; j < 8; ++j) Ash[p][(b0 + j) * 72 + lane] = (unsigned short)pA0[p][j];
        #pragma unroll
        for (int j = 0; j < 8; ++j) Ash[p][(b0 + 8 + j) * 72 + lane] = (unsigned short)pA1[p][j];
        // A slot p consumed -> refill with kt+2
        if (kt + 2 < 9) loadA(kt + 2, pA0[p], pA1[p]);
        // stage B: 4 x ds_write_b64, rows o_i = i*16+orow, k-chunk c16
        #pragma unroll
        for (int i = 0; i < 4; ++i) {
            *(short4_t*)&Bsh[p][(i * 16 + orow) * 72 + c16 * 4] = bq[i];
        }
        // own LDS writes visible, then barrier; do NOT drain vmcnt
        asm volatile("s_waitcnt lgkmcnt(0)" ::: "memory");
        __builtin_amdgcn_s_barrier();
        __builtin_amdgcn_sched_barrier(0);
        // MFMA phase
        #pragma unroll
        for (int ks = 0; ks < 2; ++ks) {
            int kof = ks * 32 + (lane >> 4) * 8;
            short8 a0 = *(const short8*)&Ash[p][(wm * 32 + (lane & 15)) * 72 + kof];
            short8 a1 = *(const short8*)&Ash[p][(wm * 32 + 16 + (lane & 15)) * 72 + kof];
            short8 q0 = *(const short8*)&Bsh[p][(wn * 32 + (lane & 15)) * 72 + kof];
            short8 q1 = *(const short8*)&Bsh[p][(wn * 32 + 16 + (lane & 15)) * 72 + kof];
            acc[0][0] = __builtin_amdgcn_mfma_f32_16x16x32_bf16(a0, q0, acc[0][0], 0, 0, 0);
            acc[0][1] = __builtin_amdgcn_mfma_f32_16x16x32_bf16(a0, q1, acc[0][1], 0, 0, 0);
            acc[1][0] = __builtin_amdgcn_mfma_f32_16x16x32_bf16(a1, q0, acc[1][0], 0, 0, 0);
            acc[1][1] = __builtin_amdgcn_mfma_f32_16x16x32_bf16(a1, q1, acc[1][1], 0, 0, 0);
        }
        // convert next round's B (its loads are ~2 rounds old -> no stall)
        if (kt + 1 < 9) {
            #pragma unroll
            for (int i = 0; i < 4; ++i) bq[i] = cvt4(bf[(kt + 1) & 1][i]);
        }
    }

    // epilogue: +bias, convert to bf16, write ws2b[l][b*64+o]
    const int col = lane & 15;
    const int rq  = (lane >> 4) * 4;
    #pragma unroll
    for (int j = 0; j < 2; ++j) {
        int n = wn * 32 + j * 16 + col;
        float bv = bias[n * 1024 + l];
        #pragma unroll
        for (int i = 0; i < 2; ++i) {
            int mbase = wm * 32 + i * 16 + rq;
            #pragma unroll
            for (int q = 0; q < 4; ++q) {
                ws2b[(size_t)l * 4096 + (size_t)(mbase + q) * 64 + n] = f2bf(acc[i][j][q] + bv);
            }
        }
    }
}

// ---------------------------------------------------------------------------
// Kernel 3: ws2b[1024 l][4096 m] bf16 -> out[4096 m][1024 l] f32
// ---------------------------------------------------------------------------
__global__ __launch_bounds__(256) void k_out(const unsigned short* __restrict__ ws2b,
                                             float* __restrict__ out) {
    const int bx = blockIdx.x;
    const int lt = bx & 15;    // l tile (16)
    const int mt = bx >> 4;    // m tile (64)
    const int t  = threadIdx.x;
    __shared__ float T[64 * 65];
    const int l0 = lt * 64, m0 = mt * 64;

    #pragma unroll
    for (int i = 0; i < 2; ++i) {
        int s  = t + i * 256;       // 0..511
        int lr = s >> 3;            // 0..63
        int mc = (s & 7) * 8;       // 0..56
        short8 v = *(const short8*)&ws2b[(size_t)(l0 + lr) * 4096 + m0 + mc];
        #pragma unroll
        for (int j = 0; j < 8; ++j) {
            union { unsigned int u; float f; } w;
            w.u = ((unsigned int)(unsigned short)v[j]) << 16;
            T[lr * 65 + mc + j] = w.f;
        }
    }
    __syncthreads();
    #pragma unroll
    for (int i = 0; i < 4; ++i) {
        int s  = t + i * 256;       // 0..1023
        int mr = s >> 4;            // 0..63
        int lc = (s & 15) * 4;
        f32x4 v;
        v[0] = T[(lc + 0) * 65 + mr];
        v[1] = T[(lc + 1) * 65 + mr];
        v[2] = T[(lc + 2) * 65 + mr];
        v[3] = T[(lc + 3) * 65 + mr];
        *(f32x4*)(out + (size_t)(m0 + mr) * 1024 + l0 + lc) = v;
    }
}

// ---------------------------------------------------------------------------
// Fallback: naive direct conv (used only if ws_size too small)
// ---------------------------------------------------------------------------
__global__ __launch_bounds__(256) void k_naive(const float* __restrict__ x,
                                               const float* __restrict__ wgt,
                                               const float* __restrict__ bias,
                                               float* __restrict__ out) {
    int idx = blockIdx.x * 256 + threadIdx.x;
    int ow = idx & 31, oh = (idx >> 5) & 31, o = (idx >> 10) & 63, b = idx >> 16;
    float acc = bias[(o * 32 + oh) * 32 + ow];
    const float* wp = wgt + ((size_t)(oh * 32 + ow) * 64 + o) * 576;
    for (int c = 0; c < 64; ++c) {
        for (int kh = 0; kh < 3; ++kh) {
            int hh = oh + kh - 1;
            if ((unsigned)hh >= 32u) continue;
            for (int kw = 0; kw < 3; ++kw) {
                int ww = ow + kw - 1;
                if ((unsigned)ww >= 32u) continue;
                acc += x[((size_t)(b * 64 + c) * 32 + hh) * 32 + ww] * wp[c * 9 + kh * 3 + kw];
            }
        }
    }
    out[idx] = acc;
}

extern "C" void kernel_launch(void* const* d_in, const int* in_sizes, int n_in,
                              void* d_out, int out_size, void* d_ws, size_t ws_size,
                              hipStream_t stream) {
    const float* x    = (const float*)d_in[0];
    const float* wgt  = (const float*)d_in[1];
    const float* bias = (const float*)d_in[2];
    float* out = (float*)d_out;

    const size_t xt_bytes  = (size_t)32 * 32 * 64 * 64 * 2;   // 8.39 MB
    const size_t ws2_bytes = (size_t)1024 * 4096 * 2;         // 8.39 MB (bf16)

    if (ws_size >= xt_bytes + ws2_bytes) {
        unsigned short* xt   = (unsigned short*)d_ws;
        unsigned short* ws2b = (unsigned short*)((char*)d_ws + xt_bytes);
        k_xt<<<dim3(32, 8, 4), 256, 0, stream>>>(x, xt);
        k_main<<<1024, 256, 0, stream>>>(wgt, xt, bias, ws2b);
        k_out<<<1024, 256, 0, stream>>>(ws2b, out);
    } else {
        k_naive<<<(64 * 64 * 32 * 32) / 256, 256, 0, stream>>>(x, wgt, bias, out);
    }
}

// Round 11
// 44.329 us; speedup vs baseline: 1.2609x; 1.0424x over previous
//
#include <hip/hip_runtime.h>
#include <hip/hip_bf16.h>

typedef __attribute__((ext_vector_type(8))) short short8;
typedef __attribute__((ext_vector_type(4))) float f32x4;

// fp32 -> bf16 round-to-nearest-even (finite inputs)
__device__ __forceinline__ unsigned short f2bf(float f) {
    union { float f; unsigned int u; } v; v.f = f;
    unsigned int u = v.u;
    u = (u + 0x7FFFu + ((u >> 16) & 1u)) >> 16;
    return (unsigned short)u;
}

// 8x f32 -> short8 bf16 via packed RNE converts (v_cvt_pk_bf16_f32)
__device__ __forceinline__ short8 cvt8(const f32x4 a, const f32x4 b) {
    union { __hip_bfloat162 h[4]; short8 s; } r;
    r.h[0] = __float22bfloat162_rn(make_float2(a[0], a[1]));
    r.h[1] = __float22bfloat162_rn(make_float2(a[2], a[3]));
    r.h[2] = __float22bfloat162_rn(make_float2(b[0], b[1]));
    r.h[3] = __float22bfloat162_rn(make_float2(b[2], b[3]));
    return r.s;
}

// ---------------------------------------------------------------------------
// Kernel 1: x[b][c][h][w] f32 -> xt[h][w][c][b] bf16.
// 1024 blocks (h x cgroup x b-quarter) = 4 blocks/CU for streaming TLP.
// ---------------------------------------------------------------------------
__global__ __launch_bounds__(256) void k_xt(const float* __restrict__ x,
                                            unsigned short* __restrict__ xt) {
    const int h  = blockIdx.x;   // 0..31
    const int cg = blockIdx.y;   // 0..7
    const int bq = blockIdx.z;   // 0..3
    const int t  = threadIdx.x;
    __shared__ unsigned short L[32 * 136];  // [w][c*16+b], padded stride

    #pragma unroll
    for (int i = 0; i < 4; ++i) {
        int s   = t + i * 256;        // 0..1023
        int row = s >> 3;             // 0..127 -> (b,c)
        int wq  = s & 7;
        int b = row >> 3, c = row & 7;
        const f32x4 v = *(const f32x4*)(x + (((size_t)((bq * 16 + b) * 64 + cg * 8 + c) * 32 + h) * 32 + wq * 4));
        int base = c * 16 + b;
        L[(wq * 4 + 0) * 136 + base] = f2bf(v[0]);
        L[(wq * 4 + 1) * 136 + base] = f2bf(v[1]);
        L[(wq * 4 + 2) * 136 + base] = f2bf(v[2]);
        L[(wq * 4 + 3) * 136 + base] = f2bf(v[3]);
    }
    __syncthreads();
    #pragma unroll
    for (int i = 0; i < 2; ++i) {
        int s  = t + i * 256;   // 0..511
        int w  = s >> 4;        // 0..31
        int c  = (s >> 1) & 7;  // 0..7
        int b8 = s & 1;         // 0..1
        short8 v = *(const short8*)&L[w * 136 + c * 16 + b8 * 8];
        *(short8*)(xt + (((size_t)(h * 32 + w) * 64 + cg * 8 + c) * 64 + bq * 16 + b8 * 8)) = v;
    }
}

// ---------------------------------------------------------------------------
// Kernel 2: per-location GEMM. 1024 blocks (one per l), 256 threads,
// 4 blocks/CU. Double-buffered LDS; 2-round-deep prefetch (fully unrolled
// kt loop so all slot indices are static); raw barrier, loads stay in
// flight. Writes ws2b[l][b][o] bf16 coalesced.
// ---------------------------------------------------------------------------
__global__ __launch_bounds__(256, 4) void k_main(const float* __restrict__ wgt,
                                                 const unsigned short* __restrict__ xt,
                                                 const float* __restrict__ bias,
                                                 unsigned short* __restrict__ ws2b) {
    const int bid = blockIdx.x;
    const int l   = (bid & 7) * 128 + (bid >> 3);   // bijective XCD swizzle
    const int oh = l >> 5, ow = l & 31;
    const int t  = threadIdx.x;
    const int wave = t >> 6, lane = t & 63;
    const int wm = wave >> 1, wn = wave & 1;

    __shared__ unsigned short Ash[2][64 * 72];  // [b][k], +8 pad
    __shared__ unsigned short Bsh[2][64 * 72];  // [o][k], +8 pad

    f32x4 acc[2][2];
    #pragma unroll
    for (int i = 0; i < 2; ++i)
        #pragma unroll
        for (int j = 0; j < 2; ++j)
            acc[i][j] = (f32x4){0.f, 0.f, 0.f, 0.f};

    const int b0 = wave * 16;
    const int o  = t >> 2, kp = t & 3;
    const float* bbase = wgt + (size_t)l * 36864 + o * 576 + kp * 16;

    auto loadA = [&](int kt, short8& va, short8& vb) {
        int kk = kt * 64 + lane;      // 0..575
        int c  = kk / 9;
        int r  = kk - c * 9;
        int kh = r / 3;
        int kw = r - kh * 3;
        int hh = oh + kh - 1;
        int ww = ow + kw - 1;
        va = (short8){0,0,0,0,0,0,0,0};
        vb = (short8){0,0,0,0,0,0,0,0};
        if ((unsigned)hh < 32u && (unsigned)ww < 32u) {
            const unsigned short* src = xt + (((size_t)(hh * 32 + ww) * 64 + c) * 64 + b0);
            va = *(const short8*)src;
            vb = *(const short8*)(src + 8);
        }
    };
    auto loadB = [&](int kt, f32x4 (&bf)[4]) {
        const f32x4* bp = (const f32x4*)(bbase + kt * 64);
        bf[0] = bp[0]; bf[1] = bp[1]; bf[2] = bp[2]; bf[3] = bp[3];
    };

    // 2-deep prefetch slots (all indices static after full unroll)
    short8 pA0[2], pA1[2];
    f32x4 bf[2][4];
    short8 bq0, bq1;

    loadA(0, pA0[0], pA1[0]);
    loadB(0, bf[0]);
    loadA(1, pA0[1], pA1[1]);
    loadB(1, bf[1]);
    bq0 = cvt8(bf[0][0], bf[0][1]);
    bq1 = cvt8(bf[0][2], bf[0][3]);

    #pragma unroll
    for (int kt = 0; kt < 9; ++kt) {
        const int p = kt & 1;
        // B slot p was consumed by cvt at end of round kt-1 -> refill with kt+2
        if (kt + 2 < 9) loadB(kt + 2, bf[p]);
        // stage A ([b][k] b16 scatter) — vmcnt wait for round-kt A lands here
        #pragma unroll
        for (int j = 0; j < 8; ++j) Ash[p][(b0 + j) * 72 + lane] = (unsigned short)pA0[p][j];
        #pragma unroll
        for (int j = 0; j < 8; ++j) Ash[p][(b0 + 8 + j) * 72 + lane] = (unsigned short)pA1[p][j];
        // A slot p consumed -> refill with kt+2
        if (kt + 2 < 9) loadA(kt + 2, pA0[p], pA1[p]);
        // stage B (pre-converted registers)
        {
            unsigned short* bdst = &Bsh[p][o * 72 + kp * 16];
            *(short8*)bdst       = bq0;
            *(short8*)(bdst + 8) = bq1;
        }
        // own LDS writes visible, then barrier; do NOT drain vmcnt
        asm volatile("s_waitcnt lgkmcnt(0)" ::: "memory");
        __builtin_amdgcn_s_barrier();
        __builtin_amdgcn_sched_barrier(0);
        // MFMA phase
        #pragma unroll
        for (int ks = 0; ks < 2; ++ks) {
            int kof = ks * 32 + (lane >> 4) * 8;
            short8 a0 = *(const short8*)&Ash[p][(wm * 32 + (lane & 15)) * 72 + kof];
            short8 a1 = *(const short8*)&Ash[p][(wm * 32 + 16 + (lane & 15)) * 72 + kof];
            short8 q0 = *(const short8*)&Bsh[p][(wn * 32 + (lane & 15)) * 72 + kof];
            short8 q1 = *(const short8*)&Bsh[p][(wn * 32 + 16 + (lane & 15)) * 72 + kof];
            acc[0][0] = __builtin_amdgcn_mfma_f32_16x16x32_bf16(a0, q0, acc[0][0], 0, 0, 0);
            acc[0][1] = __builtin_amdgcn_mfma_f32_16x16x32_bf16(a0, q1, acc[0][1], 0, 0, 0);
            acc[1][0] = __builtin_amdgcn_mfma_f32_16x16x32_bf16(a1, q0, acc[1][0], 0, 0, 0);
            acc[1][1] = __builtin_amdgcn_mfma_f32_16x16x32_bf16(a1, q1, acc[1][1], 0, 0, 0);
        }
        // convert next round's B (its loads are ~2 rounds old -> no stall)
        if (kt + 1 < 9) {
            bq0 = cvt8(bf[(kt + 1) & 1][0], bf[(kt + 1) & 1][1]);
            bq1 = cvt8(bf[(kt + 1) & 1][2], bf[(kt + 1) & 1][3]);
        }
    }

    // epilogue: +bias, convert to bf16, write ws2b[l][b*64+o]
    const int col = lane & 15;
    const int rq  = (lane >> 4) * 4;
    #pragma unroll
    for (int j = 0; j < 2; ++j) {
        int n = wn * 32 + j * 16 + col;
        float bv = bias[n * 1024 + l];
        #pragma unroll
        for (int i = 0; i < 2; ++i) {
            int mbase = wm * 32 + i * 16 + rq;
            #pragma unroll
            for (int q = 0; q < 4; ++q) {
                ws2b[(size_t)l * 4096 + (size_t)(mbase + q) * 64 + n] = f2bf(acc[i][j][q] + bv);
            }
        }
    }
}

// ---------------------------------------------------------------------------
// Kernel 3: ws2b[1024 l][4096 m] bf16 -> out[4096 m][1024 l] f32
// ---------------------------------------------------------------------------
__global__ __launch_bounds__(256) void k_out(const unsigned short* __restrict__ ws2b,
                                             float* __restrict__ out) {
    const int bx = blockIdx.x;
    const int lt = bx & 15;    // l tile (16)
    const int mt = bx >> 4;    // m tile (64)
    const int t  = threadIdx.x;
    __shared__ float T[64 * 65];
    const int l0 = lt * 64, m0 = mt * 64;

    #pragma unroll
    for (int i = 0; i < 2; ++i) {
        int s  = t + i * 256;       // 0..511
        int lr = s >> 3;            // 0..63
        int mc = (s & 7) * 8;       // 0..56
        short8 v = *(const short8*)&ws2b[(size_t)(l0 + lr) * 4096 + m0 + mc];
        #pragma unroll
        for (int j = 0; j < 8; ++j) {
            union { unsigned int u; float f; } w;
            w.u = ((unsigned int)(unsigned short)v[j]) << 16;
            T[lr * 65 + mc + j] = w.f;
        }
    }
    __syncthreads();
    #pragma unroll
    for (int i = 0; i < 4; ++i) {
        int s  = t + i * 256;       // 0..1023
        int mr = s >> 4;            // 0..63
        int lc = (s & 15) * 4;
        f32x4 v;
        v[0] = T[(lc + 0) * 65 + mr];
        v[1] = T[(lc + 1) * 65 + mr];
        v[2] = T[(lc + 2) * 65 + mr];
        v[3] = T[(lc + 3) * 65 + mr];
        *(f32x4*)(out + (size_t)(m0 + mr) * 1024 + l0 + lc) = v;
    }
}

// ---------------------------------------------------------------------------
// Fallback: naive direct conv (used only if ws_size too small)
// ---------------------------------------------------------------------------
__global__ __launch_bounds__(256) void k_naive(const float* __restrict__ x,
                                               const float* __restrict__ wgt,
                                               const float* __restrict__ bias,
                                               float* __restrict__ out) {
    int idx = blockIdx.x * 256 + threadIdx.x;
    int ow = idx & 31, oh = (idx >> 5) & 31, o = (idx >> 10) & 63, b = idx >> 16;
    float acc = bias[(o * 32 + oh) * 32 + ow];
    const float* wp = wgt + ((size_t)(oh * 32 + ow) * 64 + o) * 576;
    for (int c = 0; c < 64; ++c) {
        for (int kh = 0; kh < 3; ++kh) {
            int hh = oh + kh - 1;
            if ((unsigned)hh >= 32u) continue;
            for (int kw = 0; kw < 3; ++kw) {
                int ww = ow + kw - 1;
                if ((unsigned)ww >= 32u) continue;
                acc += x[((size_t)(b * 64 + c) * 32 + hh) * 32 + ww] * wp[c * 9 + kh * 3 + kw];
            }
        }
    }
    out[idx] = acc;
}

extern "C" void kernel_launch(void* const* d_in, const int* in_sizes, int n_in,
                              void* d_out, int out_size, void* d_ws, size_t ws_size,
                              hipStream_t stream) {
    const float* x    = (const float*)d_in[0];
    const float* wgt  = (const float*)d_in[1];
    const float* bias = (const float*)d_in[2];
    float* out = (float*)d_out;

    const size_t xt_bytes  = (size_t)32 * 32 * 64 * 64 * 2;   // 8.39 MB
    const size_t ws2_bytes = (size_t)1024 * 4096 * 2;         // 8.39 MB (bf16)

    if (ws_size >= xt_bytes + ws2_bytes) {
        unsigned short* xt   = (unsigned short*)d_ws;
        unsigned short* ws2b = (unsigned short*)((char*)d_ws + xt_bytes);
        k_xt<<<dim3(32, 8, 4), 256, 0, stream>>>(x, xt);
        k_main<<<1024, 256, 0, stream>>>(wgt, xt, bias, ws2b);
        k_out<<<1024, 256, 0, stream>>>(ws2b, out);
    } else {
        k_naive<<<(64 * 64 * 32 * 32) / 256, 256, 0, stream>>>(x, wgt, bias, out);
    }
}